// Round 1
// baseline (751.049 us; speedup 1.0000x reference)
//
#include <hip/hip_runtime.h>

#define RFL(v) __builtin_amdgcn_readfirstlane(v)

constexpr int D = 64;
constexpr int MSG_K = 32;   // edges per wave in msg kernel (amortizes W register reload)
constexpr int SL_K = 8;     // nodes per wave in selfloop kernel

// ---- edge counting: cnt[(dst,rel)] for mean-norm + per-relation histogram ----
__global__ __launch_bounds__(256) void count_kernel(
    const int* __restrict__ dst, const int* __restrict__ et,
    int* __restrict__ cnt, int* __restrict__ hist, int E, int R) {
  __shared__ int lh[128];
  if ((int)threadIdx.x < R) lh[threadIdx.x] = 0;
  __syncthreads();
  int e = blockIdx.x * blockDim.x + threadIdx.x;
  if (e < E) {
    int r = et[e];
    int d = dst[e];
    atomicAdd(&cnt[(long)d * R + r], 1);
    atomicAdd(&lh[r], 1);
  }
  __syncthreads();
  if ((int)threadIdx.x < R) {
    int c = lh[threadIdx.x];
    if (c) atomicAdd(&hist[threadIdx.x], c);
  }
}

// ---- exclusive prefix over R=65 relation counts -> scatter cursors ----
__global__ void prefix_kernel(const int* __restrict__ hist, int* __restrict__ cursor, int R) {
  if (threadIdx.x == 0 && blockIdx.x == 0) {
    int run = 0;
    for (int r = 0; r < R; ++r) { cursor[r] = run; run += hist[r]; }
  }
}

// ---- counting-sort scatter: edges grouped by relation; pre-gather src/dst/norm ----
__global__ __launch_bounds__(256) void scatter_kernel(
    const int* __restrict__ src, const int* __restrict__ dst, const int* __restrict__ et,
    const int* __restrict__ cnt, int* __restrict__ cursor,
    int* __restrict__ ssrc, int* __restrict__ sdst, int* __restrict__ set_,
    float* __restrict__ snorm, int E, int R) {
  __shared__ int lh[128];
  __shared__ int lbase[128];
  if ((int)threadIdx.x < R) lh[threadIdx.x] = 0;
  __syncthreads();
  int e = blockIdx.x * blockDim.x + threadIdx.x;
  int r = 0, lr = 0, s = 0, d = 0;
  bool valid = (e < E);
  if (valid) {
    r = et[e]; s = src[e]; d = dst[e];
    lr = atomicAdd(&lh[r], 1);   // LDS atomic: within-block rank
  }
  __syncthreads();
  if ((int)threadIdx.x < R) {
    int c = lh[threadIdx.x];
    if (c) lbase[threadIdx.x] = atomicAdd(&cursor[threadIdx.x], c);  // block base
  }
  __syncthreads();
  if (valid) {
    int pos = lbase[r] + lr;
    ssrc[pos] = s;
    sdst[pos] = d;
    set_[pos] = r;
    int c = cnt[(long)d * R + r];
    snorm[pos] = 1.0f / (float)(c > 0 ? c : 1);
  }
}

// ---- per-edge matvec with register-cached W column, atomic mean-aggregate ----
// lane = output dim h. W[r] column h lives in 64 VGPRs; reloaded only when the
// relation changes (edges are sorted by relation -> ~once per wave).
// x-row address is wave-uniform (readfirstlane'd src) -> scalar-load broadcast.
__global__ __launch_bounds__(256) void msg_kernel(
    const float* __restrict__ x, const float* __restrict__ W,
    const int* __restrict__ ssrc, const int* __restrict__ sdst,
    const int* __restrict__ set_, const float* __restrict__ snorm,
    float* __restrict__ agg, int E) {
  const int lane = threadIdx.x & 63;
  const int wave = RFL(blockIdx.x * (int)(blockDim.x >> 6) + (int)(threadIdx.x >> 6));
  long base = (long)wave * MSG_K;
  if (base >= E) return;
  long end = base + MSG_K;
  if (end > E) end = E;
  int rc = -1;
  float w[D];
  for (long i = base; i < end; ++i) {
    int s = RFL(ssrc[i]);
    int d = RFL(sdst[i]);
    int r = RFL(set_[i]);
    float nm = __int_as_float(RFL(__float_as_int(snorm[i])));
    if (r != rc) {              // uniform branch; taken ~once per wave
      rc = r;
      const float* wp = W + (long)r * (D * D) + lane;
#pragma unroll
      for (int k = 0; k < D; ++k) w[k] = wp[(long)k * D];  // coalesced column load
    }
    const float4* xr = (const float4*)(x + (long)s * D);   // uniform address
    float acc = 0.f;
#pragma unroll
    for (int k = 0; k < D / 4; ++k) {
      float4 xv = xr[k];
      acc = fmaf(xv.x, w[4 * k + 0], acc);
      acc = fmaf(xv.y, w[4 * k + 1], acc);
      acc = fmaf(xv.z, w[4 * k + 2], acc);
      acc = fmaf(xv.w, w[4 * k + 3], acc);
    }
    atomicAdd(&agg[(long)d * D + lane], acc * nm);
  }
}

// ---- out = relu(agg + x @ Wl), Wl column register-cached (shared by all waves) ----
__global__ __launch_bounds__(256) void selfloop_kernel(
    const float* __restrict__ x, const float* __restrict__ Wl,
    const float* __restrict__ agg, float* __restrict__ out, int N) {
  const int lane = threadIdx.x & 63;
  const int wave = RFL(blockIdx.x * (int)(blockDim.x >> 6) + (int)(threadIdx.x >> 6));
  long base = (long)wave * SL_K;
  if (base >= N) return;
  long end = base + SL_K;
  if (end > N) end = N;
  float w[D];
  const float* wp = Wl + lane;
#pragma unroll
  for (int k = 0; k < D; ++k) w[k] = wp[(long)k * D];
  for (long n = base; n < end; ++n) {
    float acc = agg[n * D + lane];
    const float4* xr = (const float4*)(x + n * D);
#pragma unroll
    for (int k = 0; k < D / 4; ++k) {
      float4 xv = xr[k];
      acc = fmaf(xv.x, w[4 * k + 0], acc);
      acc = fmaf(xv.y, w[4 * k + 1], acc);
      acc = fmaf(xv.z, w[4 * k + 2], acc);
      acc = fmaf(xv.w, w[4 * k + 3], acc);
    }
    out[n * D + lane] = fmaxf(acc, 0.0f);
  }
}

extern "C" void kernel_launch(void* const* d_in, const int* in_sizes, int n_in,
                              void* d_out, int out_size, void* d_ws, size_t ws_size,
                              hipStream_t stream) {
  const float* x   = (const float*)d_in[0];
  const int* src   = (const int*)d_in[1];
  const int* dst   = (const int*)d_in[2];
  const int* et    = (const int*)d_in[3];
  const float* W1  = (const float*)d_in[4];
  const float* Wl1 = (const float*)d_in[5];
  const float* W2  = (const float*)d_in[6];
  const float* Wl2 = (const float*)d_in[7];
  float* out = (float*)d_out;

  const int N = in_sizes[0] / D;
  const int E = in_sizes[1];
  const int R = in_sizes[4] / (D * D);

  // workspace carve-up (~52 MB total)
  char* ws = (char*)d_ws;
  size_t off = 0;
  auto alloc = [&](size_t bytes) -> void* {
    void* p = (void*)(ws + off);
    off += (bytes + 255) & ~(size_t)255;
    return p;
  };
  int*   cnt    = (int*)alloc((size_t)N * R * sizeof(int));
  int*   hist   = (int*)alloc((size_t)R * sizeof(int));
  int*   cursor = (int*)alloc((size_t)R * sizeof(int));
  int*   ssrc   = (int*)alloc((size_t)E * sizeof(int));
  int*   sdst   = (int*)alloc((size_t)E * sizeof(int));
  int*   set_   = (int*)alloc((size_t)E * sizeof(int));
  float* snorm  = (float*)alloc((size_t)E * sizeof(float));
  float* agg    = (float*)alloc((size_t)N * D * sizeof(float));
  float* h      = (float*)alloc((size_t)N * D * sizeof(float));
  (void)ws_size; (void)n_in; (void)out_size;

  const int eb = (E + 255) / 256;
  const int msg_waves = (E + MSG_K - 1) / MSG_K;
  const int msg_blocks = (msg_waves + 3) / 4;
  const int sl_waves = (N + SL_K - 1) / SL_K;
  const int sl_blocks = (sl_waves + 3) / 4;

  // ---- shared preprocessing (same edges for both layers) ----
  hipMemsetAsync(cnt, 0, (size_t)N * R * sizeof(int), stream);
  hipMemsetAsync(hist, 0, (size_t)R * sizeof(int), stream);
  count_kernel<<<eb, 256, 0, stream>>>(dst, et, cnt, hist, E, R);
  prefix_kernel<<<1, 64, 0, stream>>>(hist, cursor, R);
  scatter_kernel<<<eb, 256, 0, stream>>>(src, dst, et, cnt, cursor,
                                         ssrc, sdst, set_, snorm, E, R);

  // ---- layer 1 ----
  hipMemsetAsync(agg, 0, (size_t)N * D * sizeof(float), stream);
  msg_kernel<<<msg_blocks, 256, 0, stream>>>(x, W1, ssrc, sdst, set_, snorm, agg, E);
  selfloop_kernel<<<sl_blocks, 256, 0, stream>>>(x, Wl1, agg, h, N);

  // ---- layer 2 ----
  hipMemsetAsync(agg, 0, (size_t)N * D * sizeof(float), stream);
  msg_kernel<<<msg_blocks, 256, 0, stream>>>(h, W2, ssrc, sdst, set_, snorm, agg, E);
  selfloop_kernel<<<sl_blocks, 256, 0, stream>>>(h, Wl2, agg, out, N);
}

// Round 2
// 699.971 us; speedup vs baseline: 1.0730x; 1.0730x over previous
//
#include <hip/hip_runtime.h>

#define RFL(v) __builtin_amdgcn_readfirstlane(v)

constexpr int D = 64;
constexpr int MSG_K = 64;   // edges per wave; relation segments padded to MSG_K
constexpr int SL_K = 8;     // nodes per wave in selfloop kernel

// ---- edge counting: cnt[(dst,rel)] for mean-norm + per-relation histogram ----
__global__ __launch_bounds__(256) void count_kernel(
    const int* __restrict__ dst, const int* __restrict__ et,
    int* __restrict__ cnt, int* __restrict__ hist, int E, int R) {
  __shared__ int lh[128];
  if ((int)threadIdx.x < R) lh[threadIdx.x] = 0;
  __syncthreads();
  int e = blockIdx.x * blockDim.x + threadIdx.x;
  if (e < E) {
    int r = et[e];
    int d = dst[e];
    atomicAdd(&cnt[(long)d * R + r], 1);
    atomicAdd(&lh[r], 1);
  }
  __syncthreads();
  if ((int)threadIdx.x < R) {
    int c = lh[threadIdx.x];
    if (c) atomicAdd(&hist[threadIdx.x], c);
  }
}

// ---- padded exclusive prefix over R relation counts (single-block LDS scan) ----
// cursor[r] = sum_{r'<r} roundup(hist[r'], MSG_K)  -> every relation segment
// starts at a MSG_K-aligned offset, so each msg wave sees exactly ONE relation.
__global__ void prefix_kernel(const int* __restrict__ hist, int* __restrict__ cursor, int R) {
  __shared__ int sc[128];
  int l = threadIdx.x;
  int c = (l < R) ? ((hist[l] + MSG_K - 1) & ~(MSG_K - 1)) : 0;
  sc[l] = c;
  __syncthreads();
  for (int ofs = 1; ofs < 128; ofs <<= 1) {
    int v = (l >= ofs) ? sc[l - ofs] : 0;
    __syncthreads();
    sc[l] += v;
    __syncthreads();
  }
  if (l < R) cursor[l] = sc[l] - c;
}

// ---- counting-sort scatter into padded segments; one int4 record per edge ----
// rec = {src, dst, bitcast(norm), rel}. Pad slots stay all-zero (memset):
// norm==0 makes them contribute nothing.
__global__ __launch_bounds__(256) void scatter_kernel(
    const int* __restrict__ src, const int* __restrict__ dst, const int* __restrict__ et,
    const int* __restrict__ cnt, int* __restrict__ cursor,
    int4* __restrict__ eidx, int E, int R) {
  __shared__ int lh[128];
  __shared__ int lbase[128];
  if ((int)threadIdx.x < R) lh[threadIdx.x] = 0;
  __syncthreads();
  int e = blockIdx.x * blockDim.x + threadIdx.x;
  int r = 0, lr = 0, s = 0, d = 0;
  bool valid = (e < E);
  if (valid) {
    r = et[e]; s = src[e]; d = dst[e];
    lr = atomicAdd(&lh[r], 1);   // within-block rank
  }
  __syncthreads();
  if ((int)threadIdx.x < R) {
    int c = lh[threadIdx.x];
    if (c) lbase[threadIdx.x] = atomicAdd(&cursor[threadIdx.x], c);  // block base
  }
  __syncthreads();
  if (valid) {
    int pos = lbase[r] + lr;
    int c = cnt[(long)d * R + r];
    float norm = 1.0f / (float)(c > 0 ? c : 1);
    eidx[pos] = make_int4(s, d, __float_as_int(norm), r);
  }
}

// ---- per-edge matvec, W column register-cached (UNCONDITIONAL load) ----
// One relation per wave (padded segments). lane = output dim h.
// Edge records: lane l holds edge base+l; broadcast per edge via v_readlane.
__global__ __launch_bounds__(256) void msg_kernel(
    const float* __restrict__ x, const float* __restrict__ W,
    const int4* __restrict__ eidx, float* __restrict__ agg, int nwaves) {
  const int lane = threadIdx.x & 63;
  const int wave = blockIdx.x * 4 + ((int)threadIdx.x >> 6);
  if (wave >= nwaves) return;
  const long base = (long)wave * MSG_K;
  int4 rec = eidx[base + lane];          // coalesced: one record per lane
  const int r = RFL(rec.w);              // lane 0 is always a real edge (or 0-pad wave)
  float w[D];
  const float* wp = W + (long)r * (D * D) + lane;
#pragma unroll
  for (int k = 0; k < D; ++k) w[k] = wp[(long)k * D];  // coalesced column load -> VGPRs
#pragma unroll 2
  for (int j = 0; j < MSG_K; ++j) {
    int s = __builtin_amdgcn_readlane(rec.x, j);
    int d = __builtin_amdgcn_readlane(rec.y, j);
    float nm = __int_as_float(__builtin_amdgcn_readlane(rec.z, j));
    const float4* xr = (const float4*)(x + (long)s * D);  // uniform address
    float acc = 0.f;
#pragma unroll
    for (int k = 0; k < D / 4; ++k) {
      float4 xv = xr[k];
      acc = fmaf(xv.x, w[4 * k + 0], acc);
      acc = fmaf(xv.y, w[4 * k + 1], acc);
      acc = fmaf(xv.z, w[4 * k + 2], acc);
      acc = fmaf(xv.w, w[4 * k + 3], acc);
    }
    if (nm != 0.0f)                      // wave-uniform: skips pad slots entirely
      atomicAdd(&agg[(long)d * D + lane], acc * nm);
  }
}

// ---- out = relu(agg + x @ Wl), Wl column register-cached ----
__global__ __launch_bounds__(256) void selfloop_kernel(
    const float* __restrict__ x, const float* __restrict__ Wl,
    const float* __restrict__ agg, float* __restrict__ out, int N) {
  const int lane = threadIdx.x & 63;
  const int wave = blockIdx.x * 4 + ((int)threadIdx.x >> 6);
  long base = (long)wave * SL_K;
  if (base >= N) return;
  long end = base + SL_K;
  if (end > N) end = N;
  float w[D];
  const float* wp = Wl + lane;
#pragma unroll
  for (int k = 0; k < D; ++k) w[k] = wp[(long)k * D];
  for (long n = base; n < end; ++n) {
    float acc = agg[n * D + lane];
    const float4* xr = (const float4*)(x + n * D);
#pragma unroll
    for (int k = 0; k < D / 4; ++k) {
      float4 xv = xr[k];
      acc = fmaf(xv.x, w[4 * k + 0], acc);
      acc = fmaf(xv.y, w[4 * k + 1], acc);
      acc = fmaf(xv.z, w[4 * k + 2], acc);
      acc = fmaf(xv.w, w[4 * k + 3], acc);
    }
    out[n * D + lane] = fmaxf(acc, 0.0f);
  }
}

extern "C" void kernel_launch(void* const* d_in, const int* in_sizes, int n_in,
                              void* d_out, int out_size, void* d_ws, size_t ws_size,
                              hipStream_t stream) {
  const float* x   = (const float*)d_in[0];
  const int* src   = (const int*)d_in[1];
  const int* dst   = (const int*)d_in[2];
  const int* et    = (const int*)d_in[3];
  const float* W1  = (const float*)d_in[4];
  const float* Wl1 = (const float*)d_in[5];
  const float* W2  = (const float*)d_in[6];
  const float* Wl2 = (const float*)d_in[7];
  float* out = (float*)d_out;

  const int N = in_sizes[0] / D;
  const int E = in_sizes[1];
  const int R = in_sizes[4] / (D * D);

  // capacity with per-relation padding to MSG_K
  const int Ecap = ((E + MSG_K - 1) & ~(MSG_K - 1)) + R * MSG_K;
  const int nwaves = Ecap / MSG_K;

  char* ws = (char*)d_ws;
  size_t off = 0;
  auto alloc = [&](size_t bytes) -> void* {
    void* p = (void*)(ws + off);
    off += (bytes + 255) & ~(size_t)255;
    return p;
  };
  int*   cnt    = (int*)alloc((size_t)N * R * sizeof(int));
  int*   hist   = (int*)alloc((size_t)R * sizeof(int));
  int*   cursor = (int*)alloc((size_t)R * sizeof(int));
  int4*  eidx   = (int4*)alloc((size_t)(Ecap + MSG_K) * sizeof(int4));
  float* agg    = (float*)alloc((size_t)N * D * sizeof(float));
  float* h      = (float*)alloc((size_t)N * D * sizeof(float));
  (void)ws_size; (void)n_in; (void)out_size;

  const int eb = (E + 255) / 256;
  const int msg_blocks = (nwaves + 3) / 4;
  const int sl_waves = (N + SL_K - 1) / SL_K;
  const int sl_blocks = (sl_waves + 3) / 4;

  // ---- shared preprocessing (same edges for both layers) ----
  hipMemsetAsync(cnt, 0, (size_t)N * R * sizeof(int), stream);
  hipMemsetAsync(hist, 0, (size_t)R * sizeof(int), stream);
  hipMemsetAsync(eidx, 0, (size_t)(Ecap + MSG_K) * sizeof(int4), stream);
  count_kernel<<<eb, 256, 0, stream>>>(dst, et, cnt, hist, E, R);
  prefix_kernel<<<1, 128, 0, stream>>>(hist, cursor, R);
  scatter_kernel<<<eb, 256, 0, stream>>>(src, dst, et, cnt, cursor, eidx, E, R);

  // ---- layer 1 ----
  hipMemsetAsync(agg, 0, (size_t)N * D * sizeof(float), stream);
  msg_kernel<<<msg_blocks, 256, 0, stream>>>(x, W1, eidx, agg, nwaves);
  selfloop_kernel<<<sl_blocks, 256, 0, stream>>>(x, Wl1, agg, h, N);

  // ---- layer 2 ----
  hipMemsetAsync(agg, 0, (size_t)N * D * sizeof(float), stream);
  msg_kernel<<<msg_blocks, 256, 0, stream>>>(h, W2, eidx, agg, nwaves);
  selfloop_kernel<<<sl_blocks, 256, 0, stream>>>(h, Wl2, agg, out, N);
}